// Round 1
// baseline (5859.641 us; speedup 1.0000x reference)
//
#include <hip/hip_runtime.h>
#include <hip/hip_bf16.h>

#define N_NODES 100000
#define N_EDGES 1600000
#define N_GRAPHS 1024
#define EMB 100
#define HID 128
#define OUT_C 10
#define BN_EPS 1e-5f

// ---------------- Atom encoder: h0[n,c] = sum_f atom_emb[f, x[n,f], c] ----------------
__global__ void encoder_kernel(const int* __restrict__ x, const float* __restrict__ emb,
                               float* __restrict__ h0) {
    int gid = blockIdx.x * blockDim.x + threadIdx.x;
    int node = gid >> 7, c = gid & 127;
    if (node >= N_NODES || c >= EMB) return;
    float s = 0.f;
#pragma unroll
    for (int f = 0; f < 9; ++f) {
        int xv = x[node * 9 + f];
        s += emb[(f * 119 + xv) * EMB + c];
    }
    h0[(size_t)node * EMB + c] = s;
}

// ---------------- in-degree count (float) ----------------
__global__ void degree_kernel(const int* __restrict__ dst, float* __restrict__ cnt) {
    int e = blockIdx.x * blockDim.x + threadIdx.x;
    if (e < N_EDGES) atomicAdd(&cnt[dst[e]], 1.0f);
}

// ---------------- per-graph node count ----------------
__global__ void pool_cnt_kernel(const int* __restrict__ batch, float* __restrict__ g_cnt) {
    int n = blockIdx.x * blockDim.x + threadIdx.x;
    if (n < N_NODES) atomicAdd(&g_cnt[batch[n]], 1.0f);
}

// ---------------- scatter-add: agg[dst, :] += h[src, :] ----------------
// C4 = number of active float4 channel groups, SSTR = source row stride (floats)
template<int C4, int SSTR>
__global__ void scatter_kernel(const int* __restrict__ src, const int* __restrict__ dst,
                               const float* __restrict__ h, float* __restrict__ agg) {
    int gid = blockIdx.x * blockDim.x + threadIdx.x;
    int c4 = gid & 31;
    int e = gid >> 5;
    if (e >= N_EDGES || c4 >= C4) return;
    int s = src[e], d = dst[e];
    const float4 v = *reinterpret_cast<const float4*>(h + (size_t)s * SSTR + c4 * 4);
    float* a = agg + (size_t)d * 128 + c4 * 4;
    atomicAdd(a + 0, v.x);
    atomicAdd(a + 1, v.y);
    atomicAdd(a + 2, v.z);
    atomicAdd(a + 3, v.w);
}

// ---------------- fused SAGE node update ----------------
// out[n,:] = relu( (agg[n,:]/max(cnt,1)) @ Wl + bl + hsrc[n,:] @ Wr )
// == concat(mean, h) [K1+K2] @ [Wl; Wr] [K1+K2, 128]
// FINAL: additionally apply BN (eval) and atomically pool into g_sum[batch[n], :]
template<int K1, int K2, int KC, bool FINAL>
__launch_bounds__(256)
__global__ void node_update_kernel(
    const float* __restrict__ agg, const float* __restrict__ cnt,
    const float* __restrict__ hsrc,
    const float* __restrict__ Wl, const float* __restrict__ bl,
    const float* __restrict__ Wr,
    float* __restrict__ out,          // h1 [N,128] or g_sum [G,128]
    const int* __restrict__ batch,    // FINAL only
    const float* __restrict__ bn_gamma, const float* __restrict__ bn_beta,
    const float* __restrict__ bn_mean, const float* __restrict__ bn_var) {
    constexpr int K = K1 + K2;
    __shared__ float A_s[64][KC];     // KC multiple of 4 -> rows 16B aligned
    __shared__ float B_s[KC][128];
    __shared__ float inv_s[64];
    __shared__ int batch_s[64];

    const int tid = threadIdx.x;
    const int tx = tid & 31;   // channel group: channels tx*4 .. tx*4+3
    const int ty = tid >> 5;   // node subgroup: nodes ty*8 .. ty*8+7
    const int n0 = blockIdx.x * 64;

    if (tid < 64) {
        int node = n0 + tid;
        float c = (node < N_NODES) ? cnt[node] : 1.f;
        inv_s[tid] = 1.f / fmaxf(c, 1.f);
        if (FINAL) batch_s[tid] = (node < N_NODES) ? batch[node] : 0;
    }
    __syncthreads();

    float acc[8][4] = {};

    for (int ch = 0; ch < K / KC; ++ch) {
        const int kbase = ch * KC;
        // stage A tile: A[node][k] = k<K1 ? mean : hsrc
        for (int i = tid; i < 64 * KC; i += 256) {
            int ni = i / KC, kk = i - ni * KC;
            int node = n0 + ni, k = kbase + kk;
            float v = 0.f;
            if (node < N_NODES) {
                if (k < K1) v = agg[(size_t)node * 128 + k] * inv_s[ni];
                else        v = hsrc[(size_t)node * K2 + (k - K1)];
            }
            A_s[ni][kk] = v;
        }
        // stage B tile: B[k][c] = k<K1 ? Wl[k][c] : Wr[k-K1][c]
        for (int i = tid; i < KC * 128; i += 256) {
            int kk = i >> 7, c = i & 127, k = kbase + kk;
            B_s[kk][c] = (k < K1) ? Wl[k * 128 + c] : Wr[(k - K1) * 128 + c];
        }
        __syncthreads();

        for (int kk = 0; kk < KC; kk += 4) {
            float4 b0 = *(const float4*)&B_s[kk + 0][tx * 4];
            float4 b1 = *(const float4*)&B_s[kk + 1][tx * 4];
            float4 b2 = *(const float4*)&B_s[kk + 2][tx * 4];
            float4 b3 = *(const float4*)&B_s[kk + 3][tx * 4];
#pragma unroll
            for (int i = 0; i < 8; ++i) {
                float4 a = *(const float4*)&A_s[ty * 8 + i][kk];
                acc[i][0] += a.x * b0.x + a.y * b1.x + a.z * b2.x + a.w * b3.x;
                acc[i][1] += a.x * b0.y + a.y * b1.y + a.z * b2.y + a.w * b3.y;
                acc[i][2] += a.x * b0.z + a.y * b1.z + a.z * b2.z + a.w * b3.z;
                acc[i][3] += a.x * b0.w + a.y * b1.w + a.z * b2.w + a.w * b3.w;
            }
        }
        __syncthreads();
    }

    const float4 bias = *(const float4*)&bl[tx * 4];
    if (!FINAL) {
#pragma unroll
        for (int i = 0; i < 8; ++i) {
            int node = n0 + ty * 8 + i;
            if (node < N_NODES) {
                float4 v;
                v.x = fmaxf(acc[i][0] + bias.x, 0.f);
                v.y = fmaxf(acc[i][1] + bias.y, 0.f);
                v.z = fmaxf(acc[i][2] + bias.z, 0.f);
                v.w = fmaxf(acc[i][3] + bias.w, 0.f);
                *(float4*)&out[(size_t)node * 128 + tx * 4] = v;
            }
        }
    } else {
        // BN scale/shift per channel
        float4 ga = *(const float4*)&bn_gamma[tx * 4];
        float4 be = *(const float4*)&bn_beta[tx * 4];
        float4 mu = *(const float4*)&bn_mean[tx * 4];
        float4 va = *(const float4*)&bn_var[tx * 4];
        float sc[4], sh[4];
        sc[0] = ga.x * rsqrtf(va.x + BN_EPS); sh[0] = be.x - mu.x * sc[0];
        sc[1] = ga.y * rsqrtf(va.y + BN_EPS); sh[1] = be.y - mu.y * sc[1];
        sc[2] = ga.z * rsqrtf(va.z + BN_EPS); sh[2] = be.z - mu.z * sc[2];
        sc[3] = ga.w * rsqrtf(va.w + BN_EPS); sh[3] = be.w - mu.w * sc[3];
        float bb[4] = {bias.x, bias.y, bias.z, bias.w};
#pragma unroll
        for (int i = 0; i < 8; ++i) {
            int node = n0 + ty * 8 + i;
            if (node < N_NODES) {
                int b = batch_s[ty * 8 + i];
#pragma unroll
                for (int q = 0; q < 4; ++q) {
                    float v = fmaxf(acc[i][q] + bb[q], 0.f);
                    v = v * sc[q] + sh[q];
                    atomicAdd(&out[(size_t)b * 128 + tx * 4 + q], v);
                }
            }
        }
    }
}

// ---------------- pool finalize + MLP head + log_softmax ----------------
__global__ void head_kernel(const float* __restrict__ g_sum, const float* __restrict__ g_cnt,
                            const float* __restrict__ W1, const float* __restrict__ b1,
                            const float* __restrict__ W2, const float* __restrict__ b2,
                            float* __restrict__ out) {
    int b = blockIdx.x;
    int c = threadIdx.x;  // 128 threads
    __shared__ float g_s[128];
    __shared__ float h_s[128];
    __shared__ float l_s[10];
    float inv = 1.f / fmaxf(g_cnt[b], 1.f);
    g_s[c] = g_sum[(size_t)b * 128 + c] * inv;
    __syncthreads();
    float a = b1[c];
    for (int k = 0; k < 128; ++k) a += g_s[k] * W1[k * 128 + c];
    h_s[c] = fmaxf(a, 0.f);
    __syncthreads();
    if (c < OUT_C) {
        float l = b2[c];
        for (int k = 0; k < 128; ++k) l += h_s[k] * W2[k * OUT_C + c];
        l_s[c] = l;
    }
    __syncthreads();
    if (c < OUT_C) {
        float m = -1e30f;
        for (int j = 0; j < OUT_C; ++j) m = fmaxf(m, l_s[j]);
        float s = 0.f;
        for (int j = 0; j < OUT_C; ++j) s += expf(l_s[j] - m);
        out[b * OUT_C + c] = l_s[c] - m - logf(s);
    }
}

extern "C" void kernel_launch(void* const* d_in, const int* in_sizes, int n_in,
                              void* d_out, int out_size, void* d_ws, size_t ws_size,
                              hipStream_t stream) {
    const int* x        = (const int*)d_in[0];
    const int* ei       = (const int*)d_in[1];
    const int* batch    = (const int*)d_in[2];
    const float* emb    = (const float*)d_in[3];
    const float* W1l    = (const float*)d_in[4];
    const float* b1l    = (const float*)d_in[5];
    const float* W1r    = (const float*)d_in[6];
    const float* W2l    = (const float*)d_in[7];
    const float* b2l    = (const float*)d_in[8];
    const float* W2r    = (const float*)d_in[9];
    const float* bn_g   = (const float*)d_in[10];
    const float* bn_b   = (const float*)d_in[11];
    const float* bn_m   = (const float*)d_in[12];
    const float* bn_v   = (const float*)d_in[13];
    const float* mlpW1  = (const float*)d_in[14];
    const float* mlpb1  = (const float*)d_in[15];
    const float* mlpW2  = (const float*)d_in[16];
    const float* mlpb2  = (const float*)d_in[17];
    float* out = (float*)d_out;

    const int* src = ei;
    const int* dst = ei + N_EDGES;

    // workspace layout (floats); zeroed block first
    float* ws    = (float*)d_ws;
    float* agg   = ws;                                  // N*128
    float* g_sum = agg + (size_t)N_NODES * 128;         // G*128
    float* cnt   = g_sum + (size_t)N_GRAPHS * 128;      // N
    float* g_cnt = cnt + N_NODES;                       // G
    float* h0    = g_cnt + N_GRAPHS;                    // N*100
    float* h1    = h0 + (size_t)N_NODES * EMB;          // N*128

    size_t zero_floats = (size_t)N_NODES * 128 + (size_t)N_GRAPHS * 128 + N_NODES + N_GRAPHS;
    hipMemsetAsync(agg, 0, zero_floats * sizeof(float), stream);

    // encoder
    {
        int total = N_NODES * 128;
        encoder_kernel<<<(total + 255) / 256, 256, 0, stream>>>(x, emb, h0);
    }
    degree_kernel<<<(N_EDGES + 255) / 256, 256, 0, stream>>>(dst, cnt);
    pool_cnt_kernel<<<(N_NODES + 255) / 256, 256, 0, stream>>>(batch, g_cnt);

    // layer 1
    {
        long total = (long)N_EDGES * 32;
        scatter_kernel<25, EMB><<<(int)((total + 255) / 256), 256, 0, stream>>>(src, dst, h0, agg);
        node_update_kernel<100, 100, 40, false><<<(N_NODES + 63) / 64, 256, 0, stream>>>(
            agg, cnt, h0, W1l, b1l, W1r, h1, nullptr, nullptr, nullptr, nullptr, nullptr);
    }

    // layer 2 (+ BN + pool fused)
    hipMemsetAsync(agg, 0, (size_t)N_NODES * 128 * sizeof(float), stream);
    {
        long total = (long)N_EDGES * 32;
        scatter_kernel<32, HID><<<(int)((total + 255) / 256), 256, 0, stream>>>(src, dst, h1, agg);
        node_update_kernel<128, 128, 32, true><<<(N_NODES + 63) / 64, 256, 0, stream>>>(
            agg, cnt, h1, W2l, b2l, W2r, g_sum, batch, bn_g, bn_b, bn_m, bn_v);
    }

    // head
    head_kernel<<<N_GRAPHS, 128, 0, stream>>>(g_sum, g_cnt, mlpW1, mlpb1, mlpW2, mlpb2, out);
}

// Round 2
// 1123.559 us; speedup vs baseline: 5.2153x; 5.2153x over previous
//
#include <hip/hip_runtime.h>
#include <hip/hip_bf16.h>

#define N_NODES 100000
#define N_EDGES 1600000
#define N_GRAPHS 1024
#define EMB 100
#define HID 128
#define OUT_C 10
#define BN_EPS 1e-5f
#define SCAN_BLK 256

// ---------------- Atom encoder: h0[n,c] = sum_f atom_emb[f, x[n,f], c] ----------------
__global__ void encoder_kernel(const int* __restrict__ x, const float* __restrict__ emb,
                               float* __restrict__ h0) {
    int gid = blockIdx.x * blockDim.x + threadIdx.x;
    int node = gid >> 7, c = gid & 127;
    if (node >= N_NODES || c >= EMB) return;
    float s = 0.f;
#pragma unroll
    for (int f = 0; f < 9; ++f) {
        int xv = x[node * 9 + f];
        s += emb[(f * 119 + xv) * EMB + c];
    }
    h0[(size_t)node * EMB + c] = s;
}

// ---------------- CSR build ----------------
__global__ void count_kernel(const int* __restrict__ dst, int* __restrict__ cnt_i) {
    int e = blockIdx.x * blockDim.x + threadIdx.x;
    if (e < N_EDGES) atomicAdd(&cnt_i[dst[e]], 1);
}

// block-level inclusive scan of counts -> row_start[i+1]; block sums -> bsum
__global__ void scan1_kernel(const int* __restrict__ cnt_i, int* __restrict__ row_start,
                             int* __restrict__ bsum) {
    __shared__ int s[SCAN_BLK];
    int t = threadIdx.x;
    int i = blockIdx.x * SCAN_BLK + t;
    int v = (i < N_NODES) ? cnt_i[i] : 0;
    s[t] = v;
    __syncthreads();
    for (int off = 1; off < SCAN_BLK; off <<= 1) {
        int add = (t >= off) ? s[t - off] : 0;
        __syncthreads();
        s[t] += add;
        __syncthreads();
    }
    if (i < N_NODES) row_start[i + 1] = s[t];
    if (t == SCAN_BLK - 1) bsum[blockIdx.x] = s[t];
    if (i == 0) row_start[0] = 0;
}

// single-block scan of block sums -> exclusive offsets (in place)
__global__ void scan2_kernel(int* __restrict__ bsum, int nb) {
    __shared__ int s[512];
    int t = threadIdx.x;
    s[t] = (t < nb) ? bsum[t] : 0;
    __syncthreads();
    for (int off = 1; off < 512; off <<= 1) {
        int add = (t >= off) ? s[t - off] : 0;
        __syncthreads();
        s[t] += add;
        __syncthreads();
    }
    if (t < nb) bsum[t] = (t == 0) ? 0 : s[t - 1];
}

__global__ void scan3_kernel(int* __restrict__ row_start, const int* __restrict__ bsum) {
    int i = blockIdx.x * SCAN_BLK + threadIdx.x;
    if (i < N_NODES) row_start[i + 1] += bsum[blockIdx.x];
}

__global__ void permute_kernel(const int* __restrict__ src, const int* __restrict__ dst,
                               const int* __restrict__ row_start, int* __restrict__ fill,
                               int* __restrict__ esrc) {
    int e = blockIdx.x * blockDim.x + threadIdx.x;
    if (e >= N_EDGES) return;
    int d = dst[e];
    int pos = row_start[d] + atomicAdd(&fill[d], 1);
    esrc[pos] = src[e];
}

// ---------------- per-graph node count ----------------
__global__ void pool_cnt_kernel(const int* __restrict__ batch, float* __restrict__ g_cnt) {
    int n = blockIdx.x * blockDim.x + threadIdx.x;
    if (n < N_NODES) atomicAdd(&g_cnt[batch[n]], 1.0f);
}

// ---------------- gather-aggregate: mean[n,:] = (1/max(deg,1)) * sum_{e in CSR(n)} h[esrc[e],:]
// one wave per node; lane covers channels {lane, lane+64}; mean stored stride 128
template<int F>
__launch_bounds__(256)
__global__ void aggregate_kernel(const int* __restrict__ row_start, const int* __restrict__ esrc,
                                 const float* __restrict__ h, float* __restrict__ mean) {
    int wave = (blockIdx.x * blockDim.x + threadIdx.x) >> 6;
    int lane = threadIdx.x & 63;
    if (wave >= N_NODES) return;
    int beg = row_start[wave], end = row_start[wave + 1];
    const int c0 = lane, c1 = lane + 64;
    float a0 = 0.f, a1 = 0.f;
    int j = beg;
    for (; j + 1 < end; j += 2) {
        int s0 = esrc[j], s1 = esrc[j + 1];
        const float* r0 = h + (size_t)s0 * F;
        const float* r1 = h + (size_t)s1 * F;
        float v00 = r0[c0];
        float v10 = r1[c0];
        float v01 = (c1 < F) ? r0[c1] : 0.f;
        float v11 = (c1 < F) ? r1[c1] : 0.f;
        a0 += v00 + v10;
        a1 += v01 + v11;
    }
    if (j < end) {
        int s0 = esrc[j];
        const float* r0 = h + (size_t)s0 * F;
        a0 += r0[c0];
        if (c1 < F) a1 += r0[c1];
    }
    float inv = 1.f / fmaxf((float)(end - beg), 1.f);
    mean[(size_t)wave * 128 + c0] = a0 * inv;
    if (c1 < F) mean[(size_t)wave * 128 + c1] = a1 * inv;
}

// ---------------- fused SAGE node update ----------------
// out[n,:] = relu( mean[n,:] @ Wl + bl + hsrc[n,:] @ Wr )
// FINAL: additionally apply BN (eval) and atomically pool into g_sum[batch[n], :]
template<int K1, int K2, int KC, bool FINAL>
__launch_bounds__(256)
__global__ void node_update_kernel(
    const float* __restrict__ mean,
    const float* __restrict__ hsrc,
    const float* __restrict__ Wl, const float* __restrict__ bl,
    const float* __restrict__ Wr,
    float* __restrict__ out,          // h1 [N,128] or g_sum [G,128]
    const int* __restrict__ batch,    // FINAL only
    const float* __restrict__ bn_gamma, const float* __restrict__ bn_beta,
    const float* __restrict__ bn_mean, const float* __restrict__ bn_var) {
    constexpr int K = K1 + K2;
    __shared__ float A_s[64][KC];
    __shared__ float B_s[KC][128];
    __shared__ int batch_s[64];

    const int tid = threadIdx.x;
    const int tx = tid & 31;   // channel group: channels tx*4 .. tx*4+3
    const int ty = tid >> 5;   // node subgroup: nodes ty*8 .. ty*8+7
    const int n0 = blockIdx.x * 64;

    if (FINAL && tid < 64) {
        int node = n0 + tid;
        batch_s[tid] = (node < N_NODES) ? batch[node] : 0;
    }
    if (FINAL) __syncthreads();

    float acc[8][4] = {};

    for (int ch = 0; ch < K / KC; ++ch) {
        const int kbase = ch * KC;
        for (int i = tid; i < 64 * KC; i += 256) {
            int ni = i / KC, kk = i - ni * KC;
            int node = n0 + ni, k = kbase + kk;
            float v = 0.f;
            if (node < N_NODES) {
                if (k < K1) v = mean[(size_t)node * 128 + k];
                else        v = hsrc[(size_t)node * K2 + (k - K1)];
            }
            A_s[ni][kk] = v;
        }
        for (int i = tid; i < KC * 128; i += 256) {
            int kk = i >> 7, c = i & 127, k = kbase + kk;
            B_s[kk][c] = (k < K1) ? Wl[k * 128 + c] : Wr[(k - K1) * 128 + c];
        }
        __syncthreads();

        for (int kk = 0; kk < KC; kk += 4) {
            float4 b0 = *(const float4*)&B_s[kk + 0][tx * 4];
            float4 b1 = *(const float4*)&B_s[kk + 1][tx * 4];
            float4 b2 = *(const float4*)&B_s[kk + 2][tx * 4];
            float4 b3 = *(const float4*)&B_s[kk + 3][tx * 4];
#pragma unroll
            for (int i = 0; i < 8; ++i) {
                float4 a = *(const float4*)&A_s[ty * 8 + i][kk];
                acc[i][0] += a.x * b0.x + a.y * b1.x + a.z * b2.x + a.w * b3.x;
                acc[i][1] += a.x * b0.y + a.y * b1.y + a.z * b2.y + a.w * b3.y;
                acc[i][2] += a.x * b0.z + a.y * b1.z + a.z * b2.z + a.w * b3.z;
                acc[i][3] += a.x * b0.w + a.y * b1.w + a.z * b2.w + a.w * b3.w;
            }
        }
        __syncthreads();
    }

    const float4 bias = *(const float4*)&bl[tx * 4];
    if (!FINAL) {
#pragma unroll
        for (int i = 0; i < 8; ++i) {
            int node = n0 + ty * 8 + i;
            if (node < N_NODES) {
                float4 v;
                v.x = fmaxf(acc[i][0] + bias.x, 0.f);
                v.y = fmaxf(acc[i][1] + bias.y, 0.f);
                v.z = fmaxf(acc[i][2] + bias.z, 0.f);
                v.w = fmaxf(acc[i][3] + bias.w, 0.f);
                *(float4*)&out[(size_t)node * 128 + tx * 4] = v;
            }
        }
    } else {
        float4 ga = *(const float4*)&bn_gamma[tx * 4];
        float4 be = *(const float4*)&bn_beta[tx * 4];
        float4 mu = *(const float4*)&bn_mean[tx * 4];
        float4 va = *(const float4*)&bn_var[tx * 4];
        float sc[4], sh[4];
        sc[0] = ga.x * rsqrtf(va.x + BN_EPS); sh[0] = be.x - mu.x * sc[0];
        sc[1] = ga.y * rsqrtf(va.y + BN_EPS); sh[1] = be.y - mu.y * sc[1];
        sc[2] = ga.z * rsqrtf(va.z + BN_EPS); sh[2] = be.z - mu.z * sc[2];
        sc[3] = ga.w * rsqrtf(va.w + BN_EPS); sh[3] = be.w - mu.w * sc[3];
        float bb[4] = {bias.x, bias.y, bias.z, bias.w};
#pragma unroll
        for (int i = 0; i < 8; ++i) {
            int node = n0 + ty * 8 + i;
            if (node < N_NODES) {
                int b = batch_s[ty * 8 + i];
#pragma unroll
                for (int q = 0; q < 4; ++q) {
                    float v = fmaxf(acc[i][q] + bb[q], 0.f);
                    v = v * sc[q] + sh[q];
                    atomicAdd(&out[(size_t)b * 128 + tx * 4 + q], v);
                }
            }
        }
    }
}

// ---------------- pool finalize + MLP head + log_softmax ----------------
__global__ void head_kernel(const float* __restrict__ g_sum, const float* __restrict__ g_cnt,
                            const float* __restrict__ W1, const float* __restrict__ b1,
                            const float* __restrict__ W2, const float* __restrict__ b2,
                            float* __restrict__ out) {
    int b = blockIdx.x;
    int c = threadIdx.x;  // 128 threads
    __shared__ float g_s[128];
    __shared__ float h_s[128];
    __shared__ float l_s[10];
    float inv = 1.f / fmaxf(g_cnt[b], 1.f);
    g_s[c] = g_sum[(size_t)b * 128 + c] * inv;
    __syncthreads();
    float a = b1[c];
    for (int k = 0; k < 128; ++k) a += g_s[k] * W1[k * 128 + c];
    h_s[c] = fmaxf(a, 0.f);
    __syncthreads();
    if (c < OUT_C) {
        float l = b2[c];
        for (int k = 0; k < 128; ++k) l += h_s[k] * W2[k * OUT_C + c];
        l_s[c] = l;
    }
    __syncthreads();
    if (c < OUT_C) {
        float m = -1e30f;
        for (int j = 0; j < OUT_C; ++j) m = fmaxf(m, l_s[j]);
        float s = 0.f;
        for (int j = 0; j < OUT_C; ++j) s += expf(l_s[j] - m);
        out[b * OUT_C + c] = l_s[c] - m - logf(s);
    }
}

extern "C" void kernel_launch(void* const* d_in, const int* in_sizes, int n_in,
                              void* d_out, int out_size, void* d_ws, size_t ws_size,
                              hipStream_t stream) {
    const int* x        = (const int*)d_in[0];
    const int* ei       = (const int*)d_in[1];
    const int* batch    = (const int*)d_in[2];
    const float* emb    = (const float*)d_in[3];
    const float* W1l    = (const float*)d_in[4];
    const float* b1l    = (const float*)d_in[5];
    const float* W1r    = (const float*)d_in[6];
    const float* W2l    = (const float*)d_in[7];
    const float* b2l    = (const float*)d_in[8];
    const float* W2r    = (const float*)d_in[9];
    const float* bn_g   = (const float*)d_in[10];
    const float* bn_b   = (const float*)d_in[11];
    const float* bn_m   = (const float*)d_in[12];
    const float* bn_v   = (const float*)d_in[13];
    const float* mlpW1  = (const float*)d_in[14];
    const float* mlpb1  = (const float*)d_in[15];
    const float* mlpW2  = (const float*)d_in[16];
    const float* mlpb2  = (const float*)d_in[17];
    float* out = (float*)d_out;

    const int* src = ei;
    const int* dst = ei + N_EDGES;

    // ---- workspace layout ----
    // zero region first: [g_sum G*128 | g_cnt G | cnt_i N | fill N] (floats/ints, 4B each)
    char* wsc = (char*)d_ws;
    float* g_sum    = (float*)wsc;                               // G*128
    float* g_cnt    = g_sum + (size_t)N_GRAPHS * 128;            // G
    int*   cnt_i    = (int*)(g_cnt + N_GRAPHS);                  // N
    int*   fill     = cnt_i + N_NODES;                           // N
    float* mean     = (float*)(fill + N_NODES);                  // N*128
    float* h0       = mean + (size_t)N_NODES * 128;              // N*100
    float* h1       = h0 + (size_t)N_NODES * EMB;                // N*128
    int*   row_start= (int*)(h1 + (size_t)N_NODES * 128);        // N+1
    int*   esrc     = row_start + (N_NODES + 2);                 // E
    int*   bsum     = esrc + N_EDGES;                            // 512

    size_t zero_bytes = ((size_t)N_GRAPHS * 128 + N_GRAPHS + N_NODES + N_NODES) * 4;
    hipMemsetAsync(g_sum, 0, zero_bytes, stream);

    const int nb_scan = (N_NODES + SCAN_BLK - 1) / SCAN_BLK;   // 391

    // encoder (independent of CSR build)
    encoder_kernel<<<(N_NODES * 128 + 255) / 256, 256, 0, stream>>>(x, emb, h0);

    // CSR build
    count_kernel<<<(N_EDGES + 255) / 256, 256, 0, stream>>>(dst, cnt_i);
    scan1_kernel<<<nb_scan, SCAN_BLK, 0, stream>>>(cnt_i, row_start, bsum);
    scan2_kernel<<<1, 512, 0, stream>>>(bsum, nb_scan);
    scan3_kernel<<<nb_scan, SCAN_BLK, 0, stream>>>(row_start, bsum);
    permute_kernel<<<(N_EDGES + 255) / 256, 256, 0, stream>>>(src, dst, row_start, fill, esrc);

    pool_cnt_kernel<<<(N_NODES + 255) / 256, 256, 0, stream>>>(batch, g_cnt);

    // layer 1
    aggregate_kernel<EMB><<<(N_NODES * 64 + 255) / 256, 256, 0, stream>>>(row_start, esrc, h0, mean);
    node_update_kernel<100, 100, 40, false><<<(N_NODES + 63) / 64, 256, 0, stream>>>(
        mean, h0, W1l, b1l, W1r, h1, nullptr, nullptr, nullptr, nullptr, nullptr);

    // layer 2 (+ BN + pool fused)
    aggregate_kernel<HID><<<(N_NODES * 64 + 255) / 256, 256, 0, stream>>>(row_start, esrc, h1, mean);
    node_update_kernel<128, 128, 32, true><<<(N_NODES + 63) / 64, 256, 0, stream>>>(
        mean, h1, W2l, b2l, W2r, g_sum, batch, bn_g, bn_b, bn_m, bn_v);

    // head
    head_kernel<<<N_GRAPHS, 128, 0, stream>>>(g_sum, g_cnt, mlpW1, mlpb1, mlpW2, mlpb2, out);
}

// Round 3
// 659.717 us; speedup vs baseline: 8.8820x; 1.7031x over previous
//
#include <hip/hip_runtime.h>
#include <hip/hip_bf16.h>

#define N_NODES 100000
#define N_EDGES 1600000
#define N_GRAPHS 1024
#define EMB 100
#define HID 128
#define OUT_C 10
#define BN_EPS 1e-5f
#define SCAN_BLK 256

typedef __attribute__((ext_vector_type(8))) short bf16x8;
typedef __attribute__((ext_vector_type(4))) float f32x4;
typedef __attribute__((ext_vector_type(8))) unsigned short u16x8;

__device__ __forceinline__ unsigned short f2bf(float f) {
    __hip_bfloat16 h = __float2bfloat16(f);
    return *reinterpret_cast<unsigned short*>(&h);
}
__device__ __forceinline__ float bf2f(unsigned int u) {
    union { unsigned int ui; float f; } v; v.ui = u << 16; return v.f;
}

// ---------------- Atom encoder: h0[n,c] = sum_f atom_emb[f, x[n,f], c], bf16, zero-pad to 128 ----
__global__ void encoder_kernel(const int* __restrict__ x, const float* __restrict__ emb,
                               unsigned short* __restrict__ h0) {
    int gid = blockIdx.x * blockDim.x + threadIdx.x;
    int node = gid >> 7, c = gid & 127;
    if (node >= N_NODES) return;
    float s = 0.f;
    if (c < EMB) {
#pragma unroll
        for (int f = 0; f < 9; ++f) {
            int xv = x[node * 9 + f];
            s += emb[(f * 119 + xv) * EMB + c];
        }
    }
    h0[(size_t)node * 128 + c] = f2bf(s);
}

// ---------------- CSR build ----------------
__global__ void count_kernel(const int* __restrict__ dst, int* __restrict__ cnt_i) {
    int e = blockIdx.x * blockDim.x + threadIdx.x;
    if (e < N_EDGES) atomicAdd(&cnt_i[dst[e]], 1);
}

__global__ void scan1_kernel(const int* __restrict__ cnt_i, int* __restrict__ row_start,
                             int* __restrict__ bsum) {
    __shared__ int s[SCAN_BLK];
    int t = threadIdx.x;
    int i = blockIdx.x * SCAN_BLK + t;
    int v = (i < N_NODES) ? cnt_i[i] : 0;
    s[t] = v;
    __syncthreads();
    for (int off = 1; off < SCAN_BLK; off <<= 1) {
        int add = (t >= off) ? s[t - off] : 0;
        __syncthreads();
        s[t] += add;
        __syncthreads();
    }
    if (i < N_NODES) row_start[i + 1] = s[t];
    if (t == SCAN_BLK - 1) bsum[blockIdx.x] = s[t];
    if (i == 0) row_start[0] = 0;
}

__global__ void scan2_kernel(int* __restrict__ bsum, int nb) {
    __shared__ int s[512];
    int t = threadIdx.x;
    s[t] = (t < nb) ? bsum[t] : 0;
    __syncthreads();
    for (int off = 1; off < 512; off <<= 1) {
        int add = (t >= off) ? s[t - off] : 0;
        __syncthreads();
        s[t] += add;
        __syncthreads();
    }
    if (t < nb) bsum[t] = (t == 0) ? 0 : s[t - 1];
}

__global__ void scan3_kernel(int* __restrict__ row_start, const int* __restrict__ bsum) {
    int i = blockIdx.x * SCAN_BLK + threadIdx.x;
    if (i < N_NODES) row_start[i + 1] += bsum[blockIdx.x];
}

__global__ void permute_kernel(const int* __restrict__ src, const int* __restrict__ dst,
                               const int* __restrict__ row_start, int* __restrict__ fill,
                               int* __restrict__ esrc) {
    int e = blockIdx.x * blockDim.x + threadIdx.x;
    if (e >= N_EDGES) return;
    int d = dst[e];
    int pos = row_start[d] + atomicAdd(&fill[d], 1);
    esrc[pos] = src[e];
}

// ---------------- per-graph node count ----------------
__global__ void pool_cnt_kernel(const int* __restrict__ batch, float* __restrict__ g_cnt) {
    int n = blockIdx.x * blockDim.x + threadIdx.x;
    if (n < N_NODES) atomicAdd(&g_cnt[batch[n]], 1.0f);
}

// ---------------- weight prep: transpose to bf16 Wt[128][256], fold BN ----------------
__global__ void prep_kernel(const float* __restrict__ W1l, const float* __restrict__ W1r,
                            const float* __restrict__ W2l, const float* __restrict__ W2r,
                            const float* __restrict__ bn_g, const float* __restrict__ bn_b,
                            const float* __restrict__ bn_m, const float* __restrict__ bn_v,
                            unsigned short* __restrict__ Wt1, unsigned short* __restrict__ Wt2,
                            float* __restrict__ bn_scale, float* __restrict__ bn_shift) {
    int gid = blockIdx.x * blockDim.x + threadIdx.x;
    if (gid < 32768) {
        int n = gid >> 8, k = gid & 255;
        float v1 = 0.f;
        if (k < 100) v1 = W1l[k * 128 + n];
        else if (k >= 128 && k < 228) v1 = W1r[(k - 128) * 128 + n];
        Wt1[n * 256 + k] = f2bf(v1);
        float v2 = (k < 128) ? W2l[k * 128 + n] : W2r[(k - 128) * 128 + n];
        Wt2[n * 256 + k] = f2bf(v2);
    }
    if (gid < 128) {
        float sc = bn_g[gid] * rsqrtf(bn_v[gid] + BN_EPS);
        bn_scale[gid] = sc;
        bn_shift[gid] = bn_b[gid] - bn_m[gid] * sc;
    }
}

// ---------------- gather-aggregate (bf16): one wave per node, lane covers 2 channels ----------
__launch_bounds__(256)
__global__ void aggregate_kernel(const int* __restrict__ row_start, const int* __restrict__ esrc,
                                 const unsigned short* __restrict__ h,
                                 unsigned short* __restrict__ mean) {
    int wid = (blockIdx.x * blockDim.x + threadIdx.x) >> 6;
    int lane = threadIdx.x & 63;
    if (wid >= N_NODES) return;
    int beg = row_start[wid], end = row_start[wid + 1];
    float a0 = 0.f, a1 = 0.f;
    int j = beg;
    for (; j + 1 < end; j += 2) {
        int s0 = esrc[j], s1 = esrc[j + 1];
        unsigned int v0 = *(const unsigned int*)&h[(size_t)s0 * 128 + lane * 2];
        unsigned int v1 = *(const unsigned int*)&h[(size_t)s1 * 128 + lane * 2];
        a0 += bf2f(v0 & 0xffffu) + bf2f(v1 & 0xffffu);
        a1 += bf2f(v0 >> 16) + bf2f(v1 >> 16);
    }
    if (j < end) {
        unsigned int v0 = *(const unsigned int*)&h[(size_t)esrc[j] * 128 + lane * 2];
        a0 += bf2f(v0 & 0xffffu);
        a1 += bf2f(v0 >> 16);
    }
    float inv = 1.f / fmaxf((float)(end - beg), 1.f);
    unsigned int o = ((unsigned int)f2bf(a1 * inv) << 16) | f2bf(a0 * inv);
    *(unsigned int*)&mean[(size_t)wid * 128 + lane * 2] = o;
}

// ---------------- MFMA node update: out[64 nodes][128] = relu([mean|h] @ Wt^T + b) (+BN+pool) ----
// A tile: 64 rows x 256 k (bf16) in LDS, XOR-swizzled. B from global (L2-resident), pre-transposed.
template<bool FINAL>
__launch_bounds__(256)
__global__ void node_update_mfma(const unsigned short* __restrict__ mean,
                                 const unsigned short* __restrict__ h,
                                 const unsigned short* __restrict__ Wt,
                                 const float* __restrict__ bl,
                                 unsigned short* __restrict__ hout,   // !FINAL
                                 float* __restrict__ g_sum,           // FINAL
                                 const int* __restrict__ batch,
                                 const float* __restrict__ bn_scale,
                                 const float* __restrict__ bn_shift) {
    __shared__ unsigned short A_s[64 * 256];
    __shared__ float pool_s[8 * 128];
    __shared__ int batch_s[64];

    const int tid = threadIdx.x;
    const int n0 = blockIdx.x * 64;

    if (FINAL) {
        if (tid < 64) batch_s[tid] = batch[min(n0 + tid, N_NODES - 1)];
        for (int i = tid; i < 1024; i += 256) pool_s[i] = 0.f;
    }

    // stage A: 2048 chunks of 16B; chunk c -> row c>>5, byte (c&31)*16 (first 256B mean, next 256B h)
#pragma unroll
    for (int i = 0; i < 8; ++i) {
        int c = tid + i * 256;
        int row = c >> 5, cb = (c & 31) * 16;
        int node = n0 + row;
        u16x8 v;
        if (node < N_NODES) {
            const unsigned short* srcp = (cb < 256)
                ? (mean + (size_t)node * 128 + (cb >> 1))
                : (h + (size_t)node * 128 + ((cb - 256) >> 1));
            v = *(const u16x8*)srcp;
        } else {
#pragma unroll
            for (int q = 0; q < 8; ++q) v[q] = 0;
        }
        int sw = cb ^ ((row & 7) << 4);
        *(u16x8*)&A_s[row * 256 + (sw >> 1)] = v;
    }
    __syncthreads();

    const int lane = tid & 63;
    const int w = tid >> 6;
    const int q = lane >> 4;       // k-part 0..3
    const int r16 = lane & 15;
    const int arow = w * 16 + r16;

    f32x4 acc[8];
#pragma unroll
    for (int n = 0; n < 8; ++n) acc[n] = (f32x4){0.f, 0.f, 0.f, 0.f};

    const unsigned short* wt_lane = Wt + r16 * 256 + q * 8;
    const unsigned short* a_base = A_s + arow * 256;
    const int axor = (arow & 7) << 4;

#pragma unroll
    for (int ks = 0; ks < 8; ++ks) {
        int cb = ks * 64 + q * 16;
        bf16x8 a = *(const bf16x8*)&a_base[(cb ^ axor) >> 1];
#pragma unroll
        for (int n = 0; n < 8; ++n) {
            bf16x8 b = *(const bf16x8*)&wt_lane[n * 4096 + ks * 32];
            acc[n] = __builtin_amdgcn_mfma_f32_16x16x32_bf16(a, b, acc[n], 0, 0, 0);
        }
    }

    const int baserow = w * 16 + q * 4;
    if (!FINAL) {
#pragma unroll
        for (int n = 0; n < 8; ++n) {
            int col = n * 16 + r16;
            float bias = bl[col];
#pragma unroll
            for (int rr = 0; rr < 4; ++rr) {
                int node = n0 + baserow + rr;
                if (node < N_NODES) {
                    float v = fmaxf(acc[n][rr] + bias, 0.f);
                    hout[(size_t)node * 128 + col] = f2bf(v);
                }
            }
        }
    } else {
        const int g_lo = batch_s[0], g_hi = batch_s[63];
        const bool small_span = (g_hi - g_lo) < 8;
#pragma unroll
        for (int n = 0; n < 8; ++n) {
            int col = n * 16 + r16;
            float bias = bl[col], sc = bn_scale[col], sh = bn_shift[col];
#pragma unroll
            for (int rr = 0; rr < 4; ++rr) {
                int nl = baserow + rr;
                int node = n0 + nl;
                if (node < N_NODES) {
                    float v = fmaxf(acc[n][rr] + bias, 0.f) * sc + sh;
                    int g = batch_s[nl];
                    if (small_span) atomicAdd(&pool_s[(g - g_lo) * 128 + col], v);
                    else            atomicAdd(&g_sum[(size_t)g * 128 + col], v);
                }
            }
        }
        __syncthreads();
        if (small_span) {
            int span = g_hi - g_lo + 1;
            for (int i = tid; i < span * 128; i += 256)
                atomicAdd(&g_sum[(size_t)(g_lo + (i >> 7)) * 128 + (i & 127)], pool_s[i]);
        }
    }
}

// ---------------- pool finalize + MLP head + log_softmax ----------------
__global__ void head_kernel(const float* __restrict__ g_sum, const float* __restrict__ g_cnt,
                            const float* __restrict__ W1, const float* __restrict__ b1,
                            const float* __restrict__ W2, const float* __restrict__ b2,
                            float* __restrict__ out) {
    int b = blockIdx.x;
    int c = threadIdx.x;  // 128 threads
    __shared__ float g_s[128];
    __shared__ float h_s[128];
    __shared__ float l_s[10];
    float inv = 1.f / fmaxf(g_cnt[b], 1.f);
    g_s[c] = g_sum[(size_t)b * 128 + c] * inv;
    __syncthreads();
    float a = b1[c];
    for (int k = 0; k < 128; ++k) a += g_s[k] * W1[k * 128 + c];
    h_s[c] = fmaxf(a, 0.f);
    __syncthreads();
    if (c < OUT_C) {
        float l = b2[c];
        for (int k = 0; k < 128; ++k) l += h_s[k] * W2[k * OUT_C + c];
        l_s[c] = l;
    }
    __syncthreads();
    if (c < OUT_C) {
        float m = -1e30f;
        for (int j = 0; j < OUT_C; ++j) m = fmaxf(m, l_s[j]);
        float s = 0.f;
        for (int j = 0; j < OUT_C; ++j) s += expf(l_s[j] - m);
        out[b * OUT_C + c] = l_s[c] - m - logf(s);
    }
}

extern "C" void kernel_launch(void* const* d_in, const int* in_sizes, int n_in,
                              void* d_out, int out_size, void* d_ws, size_t ws_size,
                              hipStream_t stream) {
    const int* x        = (const int*)d_in[0];
    const int* ei       = (const int*)d_in[1];
    const int* batch    = (const int*)d_in[2];
    const float* emb    = (const float*)d_in[3];
    const float* W1l    = (const float*)d_in[4];
    const float* b1l    = (const float*)d_in[5];
    const float* W1r    = (const float*)d_in[6];
    const float* W2l    = (const float*)d_in[7];
    const float* b2l    = (const float*)d_in[8];
    const float* W2r    = (const float*)d_in[9];
    const float* bn_g   = (const float*)d_in[10];
    const float* bn_b   = (const float*)d_in[11];
    const float* bn_m   = (const float*)d_in[12];
    const float* bn_v   = (const float*)d_in[13];
    const float* mlpW1  = (const float*)d_in[14];
    const float* mlpb1  = (const float*)d_in[15];
    const float* mlpW2  = (const float*)d_in[16];
    const float* mlpb2  = (const float*)d_in[17];
    float* out = (float*)d_out;

    const int* src = ei;
    const int* dst = ei + N_EDGES;

    // ---- workspace layout (16B-aligned sections) ----
    char* p = (char*)d_ws;
    float* g_sum   = (float*)p;                 p += (size_t)N_GRAPHS * 128 * 4;   // zeroed
    float* g_cnt   = (float*)p;                 p += 4096;                          // zeroed (1024*4)
    int*   cnt_i   = (int*)p;                   p += (size_t)N_NODES * 4;          // zeroed
    int*   fill    = (int*)p;                   p += (size_t)N_NODES * 4;          // zeroed
    unsigned short* h0   = (unsigned short*)p;  p += (size_t)N_NODES * 128 * 2;
    unsigned short* h1   = (unsigned short*)p;  p += (size_t)N_NODES * 128 * 2;
    unsigned short* mean = (unsigned short*)p;  p += (size_t)N_NODES * 128 * 2;
    unsigned short* Wt1  = (unsigned short*)p;  p += 128 * 256 * 2;
    unsigned short* Wt2  = (unsigned short*)p;  p += 128 * 256 * 2;
    float* bn_scale = (float*)p;                p += 512;
    float* bn_shift = (float*)p;                p += 512;
    int*   row_start = (int*)p;                 p += (size_t)(N_NODES + 4) * 4;
    int*   esrc    = (int*)p;                   p += (size_t)N_EDGES * 4;
    int*   bsum    = (int*)p;                   p += 2048;

    size_t zero_bytes = (size_t)N_GRAPHS * 128 * 4 + 4096 + (size_t)N_NODES * 8;
    hipMemsetAsync(g_sum, 0, zero_bytes, stream);

    const int nb_scan = (N_NODES + SCAN_BLK - 1) / SCAN_BLK;   // 391

    encoder_kernel<<<(N_NODES * 128 + 255) / 256, 256, 0, stream>>>(x, emb, h0);
    prep_kernel<<<128, 256, 0, stream>>>(W1l, W1r, W2l, W2r, bn_g, bn_b, bn_m, bn_v,
                                         Wt1, Wt2, bn_scale, bn_shift);

    count_kernel<<<(N_EDGES + 255) / 256, 256, 0, stream>>>(dst, cnt_i);
    scan1_kernel<<<nb_scan, SCAN_BLK, 0, stream>>>(cnt_i, row_start, bsum);
    scan2_kernel<<<1, 512, 0, stream>>>(bsum, nb_scan);
    scan3_kernel<<<nb_scan, SCAN_BLK, 0, stream>>>(row_start, bsum);
    permute_kernel<<<(N_EDGES + 255) / 256, 256, 0, stream>>>(src, dst, row_start, fill, esrc);

    pool_cnt_kernel<<<(N_NODES + 255) / 256, 256, 0, stream>>>(batch, g_cnt);

    const int agg_blocks = (N_NODES * 64 + 255) / 256;
    const int nu_blocks = (N_NODES + 63) / 64;

    // layer 1
    aggregate_kernel<<<agg_blocks, 256, 0, stream>>>(row_start, esrc, h0, mean);
    node_update_mfma<false><<<nu_blocks, 256, 0, stream>>>(
        mean, h0, Wt1, b1l, h1, nullptr, nullptr, nullptr, nullptr);

    // layer 2 (+ BN + pool fused)
    aggregate_kernel<<<agg_blocks, 256, 0, stream>>>(row_start, esrc, h1, mean);
    node_update_mfma<true><<<nu_blocks, 256, 0, stream>>>(
        mean, h1, Wt2, b2l, nullptr, g_sum, batch, bn_scale, bn_shift);

    // head
    head_kernel<<<N_GRAPHS, 128, 0, stream>>>(g_sum, g_cnt, mlpW1, mlpb1, mlpW2, mlpb2, out);
}

// Round 4
// 552.380 us; speedup vs baseline: 10.6080x; 1.1943x over previous
//
#include <hip/hip_runtime.h>
#include <hip/hip_bf16.h>

#define N_NODES 100000
#define N_EDGES 1600000
#define N_GRAPHS 1024
#define EMB 100
#define HID 128
#define OUT_C 10
#define BN_EPS 1e-5f
#define SCAN_BLK 256

typedef __attribute__((ext_vector_type(8))) short bf16x8;
typedef __attribute__((ext_vector_type(4))) float f32x4;
typedef __attribute__((ext_vector_type(8))) unsigned short u16x8;

__device__ __forceinline__ unsigned short f2bf(float f) {
    __hip_bfloat16 h = __float2bfloat16(f);
    return *reinterpret_cast<unsigned short*>(&h);
}
__device__ __forceinline__ float bf2f(unsigned int u) {
    union { unsigned int ui; float f; } v; v.ui = u << 16; return v.f;
}

// ---------------- Atom encoder: h0[n,c] = sum_f atom_emb[f, x[n,f], c], bf16, zero-pad to 128 ----
__global__ void encoder_kernel(const int* __restrict__ x, const float* __restrict__ emb,
                               unsigned short* __restrict__ h0) {
    int gid = blockIdx.x * blockDim.x + threadIdx.x;
    int node = gid >> 7, c = gid & 127;
    if (node >= N_NODES) return;
    float s = 0.f;
    if (c < EMB) {
#pragma unroll
        for (int f = 0; f < 9; ++f) {
            int xv = x[node * 9 + f];
            s += emb[(f * 119 + xv) * EMB + c];
        }
    }
    h0[(size_t)node * 128 + c] = f2bf(s);
}

// ---------------- CSR build ----------------
__global__ void count_kernel(const int* __restrict__ dst, int* __restrict__ cnt_i) {
    int e = blockIdx.x * blockDim.x + threadIdx.x;
    if (e < N_EDGES) atomicAdd(&cnt_i[dst[e]], 1);
}

__global__ void scan1_kernel(const int* __restrict__ cnt_i, int* __restrict__ row_start,
                             int* __restrict__ bsum) {
    __shared__ int s[SCAN_BLK];
    int t = threadIdx.x;
    int i = blockIdx.x * SCAN_BLK + t;
    int v = (i < N_NODES) ? cnt_i[i] : 0;
    s[t] = v;
    __syncthreads();
    for (int off = 1; off < SCAN_BLK; off <<= 1) {
        int add = (t >= off) ? s[t - off] : 0;
        __syncthreads();
        s[t] += add;
        __syncthreads();
    }
    if (i < N_NODES) row_start[i + 1] = s[t];
    if (t == SCAN_BLK - 1) bsum[blockIdx.x] = s[t];
    if (i == 0) row_start[0] = 0;
}

__global__ void scan2_kernel(int* __restrict__ bsum, int nb) {
    __shared__ int s[512];
    int t = threadIdx.x;
    s[t] = (t < nb) ? bsum[t] : 0;
    __syncthreads();
    for (int off = 1; off < 512; off <<= 1) {
        int add = (t >= off) ? s[t - off] : 0;
        __syncthreads();
        s[t] += add;
        __syncthreads();
    }
    if (t < nb) bsum[t] = (t == 0) ? 0 : s[t - 1];
}

__global__ void scan3_kernel(int* __restrict__ row_start, const int* __restrict__ bsum) {
    int i = blockIdx.x * SCAN_BLK + threadIdx.x;
    if (i < N_NODES) row_start[i + 1] += bsum[blockIdx.x];
}

__global__ void permute_kernel(const int* __restrict__ src, const int* __restrict__ dst,
                               const int* __restrict__ row_start, int* __restrict__ fill,
                               int* __restrict__ esrc) {
    int e = blockIdx.x * blockDim.x + threadIdx.x;
    if (e >= N_EDGES) return;
    int d = dst[e];
    int pos = row_start[d] + atomicAdd(&fill[d], 1);
    esrc[pos] = src[e];
}

// ---------------- per-graph node count ----------------
__global__ void pool_cnt_kernel(const int* __restrict__ batch, float* __restrict__ g_cnt) {
    int n = blockIdx.x * blockDim.x + threadIdx.x;
    if (n < N_NODES) atomicAdd(&g_cnt[batch[n]], 1.0f);
}

// ---------------- weight prep: transpose to bf16 Wt[128][256], fold BN ----------------
__global__ void prep_kernel(const float* __restrict__ W1l, const float* __restrict__ W1r,
                            const float* __restrict__ W2l, const float* __restrict__ W2r,
                            const float* __restrict__ bn_g, const float* __restrict__ bn_b,
                            const float* __restrict__ bn_m, const float* __restrict__ bn_v,
                            unsigned short* __restrict__ Wt1, unsigned short* __restrict__ Wt2,
                            float* __restrict__ bn_scale, float* __restrict__ bn_shift) {
    int gid = blockIdx.x * blockDim.x + threadIdx.x;
    if (gid < 32768) {
        int n = gid >> 8, k = gid & 255;
        float v1 = 0.f;
        if (k < 100) v1 = W1l[k * 128 + n];
        else if (k >= 128 && k < 228) v1 = W1r[(k - 128) * 128 + n];
        Wt1[n * 256 + k] = f2bf(v1);
        float v2 = (k < 128) ? W2l[k * 128 + n] : W2r[(k - 128) * 128 + n];
        Wt2[n * 256 + k] = f2bf(v2);
    }
    if (gid < 128) {
        float sc = bn_g[gid] * rsqrtf(bn_v[gid] + BN_EPS);
        bn_scale[gid] = sc;
        bn_shift[gid] = bn_b[gid] - bn_m[gid] * sc;
    }
}

// ---------------- fused SAGE layer: gather-mean -> LDS -> MFMA -> epilogue ----------------
// 512 threads = 8 waves per block, 64 output nodes per block.
// A tile in LDS: 64 rows x 512 bytes (k 0..127 = mean, k 128..255 = own h), XOR-swizzled.
// Wave w owns output column block w (cols w*16..w*16+15); B fragments preloaded to registers.
template<bool FINAL>
__launch_bounds__(512)
__global__ void sage_layer_kernel(const int* __restrict__ row_start, const int* __restrict__ esrc,
                                  const unsigned short* __restrict__ h,
                                  const unsigned short* __restrict__ Wt,
                                  const float* __restrict__ bl,
                                  unsigned short* __restrict__ hout,   // !FINAL
                                  float* __restrict__ g_sum,           // FINAL
                                  const int* __restrict__ batch,
                                  const float* __restrict__ bn_scale,
                                  const float* __restrict__ bn_shift) {
    __shared__ unsigned short A_s[64 * 256];
    __shared__ float pool_s[8 * 128];
    __shared__ int batch_s[64];

    const int tid = threadIdx.x;
    const int n0 = blockIdx.x * 64;
    const int lane = tid & 63;
    const int w = tid >> 6;        // wave 0..7
    const int q = lane >> 4;       // 0..3
    const int r16 = lane & 15;
    char* A_c = (char*)A_s;

    // ---- B preload (issued first; latency hides under staging+gather) ----
    bf16x8 breg[8];
    const unsigned short* wt_lane = Wt + (w * 16 + r16) * 256 + q * 8;
#pragma unroll
    for (int ks = 0; ks < 8; ++ks)
        breg[ks] = *(const bf16x8*)&wt_lane[ks * 32];

    if (FINAL) {
        if (tid < 64) batch_s[tid] = batch[min(n0 + tid, N_NODES - 1)];
        for (int i = tid; i < 1024; i += 512) pool_s[i] = 0.f;
    }

    // ---- own-h staging: k-slots 128..255 (bytes 256..511 of each 512B row) ----
#pragma unroll
    for (int i = 0; i < 2; ++i) {
        int c = tid + i * 512;              // 0..1023 chunks of 16B
        int row = c >> 4;
        int cb = 256 + (c & 15) * 16;
        int node = n0 + row;
        u16x8 v;
        if (node < N_NODES) {
            v = *(const u16x8*)&h[(size_t)node * 128 + ((cb - 256) >> 1)];
        } else {
#pragma unroll
            for (int z = 0; z < 8; ++z) v[z] = 0;
        }
        *(u16x8*)(A_c + row * 512 + (cb ^ ((row & 7) << 4))) = v;
    }

    // ---- gather-mean: wave w handles local nodes w*8 .. w*8+7; lane = channel pair ----
    for (int jj = 0; jj < 8; ++jj) {
        int nl = w * 8 + jj;
        int node = n0 + nl;
        unsigned int outw = 0;
        if (node < N_NODES) {
            int beg = row_start[node], end = row_start[node + 1];
            float a0 = 0.f, a1 = 0.f, b0 = 0.f, b1 = 0.f;
            float c0 = 0.f, c1 = 0.f, d0 = 0.f, d1 = 0.f;
            int j = beg;
            for (; j + 3 < end; j += 4) {
                unsigned int v0 = *(const unsigned int*)&h[(size_t)esrc[j + 0] * 128 + lane * 2];
                unsigned int v1 = *(const unsigned int*)&h[(size_t)esrc[j + 1] * 128 + lane * 2];
                unsigned int v2 = *(const unsigned int*)&h[(size_t)esrc[j + 2] * 128 + lane * 2];
                unsigned int v3 = *(const unsigned int*)&h[(size_t)esrc[j + 3] * 128 + lane * 2];
                a0 += bf2f(v0 & 0xffffu); a1 += bf2f(v0 >> 16);
                b0 += bf2f(v1 & 0xffffu); b1 += bf2f(v1 >> 16);
                c0 += bf2f(v2 & 0xffffu); c1 += bf2f(v2 >> 16);
                d0 += bf2f(v3 & 0xffffu); d1 += bf2f(v3 >> 16);
            }
            for (; j < end; ++j) {
                unsigned int v0 = *(const unsigned int*)&h[(size_t)esrc[j] * 128 + lane * 2];
                a0 += bf2f(v0 & 0xffffu); a1 += bf2f(v0 >> 16);
            }
            float s0 = (a0 + b0) + (c0 + d0);
            float s1 = (a1 + b1) + (c1 + d1);
            float inv = 1.f / fmaxf((float)(end - beg), 1.f);
            outw = ((unsigned int)f2bf(s1 * inv) << 16) | f2bf(s0 * inv);
        }
        int cb = (lane * 4) ^ ((nl & 7) << 4);
        *(unsigned int*)(A_c + nl * 512 + cb) = outw;
    }
    __syncthreads();

    // ---- MFMA: wave w computes all 64 rows x cols [w*16, w*16+16) ----
    f32x4 acc[4];
#pragma unroll
    for (int rt = 0; rt < 4; ++rt) acc[rt] = (f32x4){0.f, 0.f, 0.f, 0.f};

#pragma unroll
    for (int ks = 0; ks < 8; ++ks) {
#pragma unroll
        for (int rt = 0; rt < 4; ++rt) {
            int arow = rt * 16 + r16;
            int cb = (ks * 64 + q * 16) ^ ((arow & 7) << 4);
            bf16x8 a = *(const bf16x8*)(A_c + arow * 512 + cb);
            acc[rt] = __builtin_amdgcn_mfma_f32_16x16x32_bf16(a, breg[ks], acc[rt], 0, 0, 0);
        }
    }

    // ---- epilogue ----
    const int col = w * 16 + r16;
    const float bias = bl[col];
    if (!FINAL) {
#pragma unroll
        for (int rt = 0; rt < 4; ++rt) {
#pragma unroll
            for (int rr = 0; rr < 4; ++rr) {
                int node = n0 + rt * 16 + q * 4 + rr;
                if (node < N_NODES) {
                    float v = fmaxf(acc[rt][rr] + bias, 0.f);
                    hout[(size_t)node * 128 + col] = f2bf(v);
                }
            }
        }
    } else {
        const float sc = bn_scale[col], sh = bn_shift[col];
        const int g_lo = batch_s[0], g_hi = batch_s[63];
        const bool small_span = (g_hi - g_lo) < 8;
#pragma unroll
        for (int rt = 0; rt < 4; ++rt) {
#pragma unroll
            for (int rr = 0; rr < 4; ++rr) {
                int nl = rt * 16 + q * 4 + rr;
                int node = n0 + nl;
                if (node < N_NODES) {
                    float v = fmaxf(acc[rt][rr] + bias, 0.f) * sc + sh;
                    int g = batch_s[nl];
                    if (small_span) atomicAdd(&pool_s[(g - g_lo) * 128 + col], v);
                    else            atomicAdd(&g_sum[(size_t)g * 128 + col], v);
                }
            }
        }
        __syncthreads();
        if (small_span) {
            int span = g_hi - g_lo + 1;
            for (int i = tid; i < span * 128; i += 512)
                atomicAdd(&g_sum[(size_t)(g_lo + (i >> 7)) * 128 + (i & 127)], pool_s[i]);
        }
    }
}

// ---------------- pool finalize + MLP head + log_softmax ----------------
__global__ void head_kernel(const float* __restrict__ g_sum, const float* __restrict__ g_cnt,
                            const float* __restrict__ W1, const float* __restrict__ b1,
                            const float* __restrict__ W2, const float* __restrict__ b2,
                            float* __restrict__ out) {
    int b = blockIdx.x;
    int c = threadIdx.x;  // 128 threads
    __shared__ float g_s[128];
    __shared__ float h_s[128];
    __shared__ float l_s[10];
    float inv = 1.f / fmaxf(g_cnt[b], 1.f);
    g_s[c] = g_sum[(size_t)b * 128 + c] * inv;
    __syncthreads();
    float a = b1[c];
    for (int k = 0; k < 128; ++k) a += g_s[k] * W1[k * 128 + c];
    h_s[c] = fmaxf(a, 0.f);
    __syncthreads();
    if (c < OUT_C) {
        float l = b2[c];
        for (int k = 0; k < 128; ++k) l += h_s[k] * W2[k * OUT_C + c];
        l_s[c] = l;
    }
    __syncthreads();
    if (c < OUT_C) {
        float m = -1e30f;
        for (int j = 0; j < OUT_C; ++j) m = fmaxf(m, l_s[j]);
        float s = 0.f;
        for (int j = 0; j < OUT_C; ++j) s += expf(l_s[j] - m);
        out[b * OUT_C + c] = l_s[c] - m - logf(s);
    }
}

extern "C" void kernel_launch(void* const* d_in, const int* in_sizes, int n_in,
                              void* d_out, int out_size, void* d_ws, size_t ws_size,
                              hipStream_t stream) {
    const int* x        = (const int*)d_in[0];
    const int* ei       = (const int*)d_in[1];
    const int* batch    = (const int*)d_in[2];
    const float* emb    = (const float*)d_in[3];
    const float* W1l    = (const float*)d_in[4];
    const float* b1l    = (const float*)d_in[5];
    const float* W1r    = (const float*)d_in[6];
    const float* W2l    = (const float*)d_in[7];
    const float* b2l    = (const float*)d_in[8];
    const float* W2r    = (const float*)d_in[9];
    const float* bn_g   = (const float*)d_in[10];
    const float* bn_b   = (const float*)d_in[11];
    const float* bn_m   = (const float*)d_in[12];
    const float* bn_v   = (const float*)d_in[13];
    const float* mlpW1  = (const float*)d_in[14];
    const float* mlpb1  = (const float*)d_in[15];
    const float* mlpW2  = (const float*)d_in[16];
    const float* mlpb2  = (const float*)d_in[17];
    float* out = (float*)d_out;

    const int* src = ei;
    const int* dst = ei + N_EDGES;

    // ---- workspace layout (16B-aligned sections) ----
    char* p = (char*)d_ws;
    float* g_sum   = (float*)p;                 p += (size_t)N_GRAPHS * 128 * 4;   // zeroed
    float* g_cnt   = (float*)p;                 p += 4096;                          // zeroed
    int*   cnt_i   = (int*)p;                   p += (size_t)N_NODES * 4;          // zeroed
    int*   fill    = (int*)p;                   p += (size_t)N_NODES * 4;          // zeroed
    unsigned short* h0   = (unsigned short*)p;  p += (size_t)N_NODES * 128 * 2;
    unsigned short* h1   = (unsigned short*)p;  p += (size_t)N_NODES * 128 * 2;
    unsigned short* Wt1  = (unsigned short*)p;  p += 128 * 256 * 2;
    unsigned short* Wt2  = (unsigned short*)p;  p += 128 * 256 * 2;
    float* bn_scale = (float*)p;                p += 512;
    float* bn_shift = (float*)p;                p += 512;
    int*   row_start = (int*)p;                 p += (size_t)(N_NODES + 4) * 4;
    int*   esrc    = (int*)p;                   p += (size_t)N_EDGES * 4;
    int*   bsum    = (int*)p;                   p += 2048;

    size_t zero_bytes = (size_t)N_GRAPHS * 128 * 4 + 4096 + (size_t)N_NODES * 8;
    hipMemsetAsync(g_sum, 0, zero_bytes, stream);

    const int nb_scan = (N_NODES + SCAN_BLK - 1) / SCAN_BLK;   // 391

    encoder_kernel<<<(N_NODES * 128 + 255) / 256, 256, 0, stream>>>(x, emb, h0);
    prep_kernel<<<128, 256, 0, stream>>>(W1l, W1r, W2l, W2r, bn_g, bn_b, bn_m, bn_v,
                                         Wt1, Wt2, bn_scale, bn_shift);

    count_kernel<<<(N_EDGES + 255) / 256, 256, 0, stream>>>(dst, cnt_i);
    scan1_kernel<<<nb_scan, SCAN_BLK, 0, stream>>>(cnt_i, row_start, bsum);
    scan2_kernel<<<1, 512, 0, stream>>>(bsum, nb_scan);
    scan3_kernel<<<nb_scan, SCAN_BLK, 0, stream>>>(row_start, bsum);
    permute_kernel<<<(N_EDGES + 255) / 256, 256, 0, stream>>>(src, dst, row_start, fill, esrc);

    pool_cnt_kernel<<<(N_NODES + 255) / 256, 256, 0, stream>>>(batch, g_cnt);

    const int nblocks = (N_NODES + 63) / 64;   // 1563

    // layer 1 (fused gather + GEMM)
    sage_layer_kernel<false><<<nblocks, 512, 0, stream>>>(
        row_start, esrc, h0, Wt1, b1l, h1, nullptr, nullptr, nullptr, nullptr);

    // layer 2 (fused gather + GEMM + BN + pool)
    sage_layer_kernel<true><<<nblocks, 512, 0, stream>>>(
        row_start, esrc, h1, Wt2, b2l, nullptr, g_sum, batch, bn_scale, bn_shift);

    // head
    head_kernel<<<N_GRAPHS, 128, 0, stream>>>(g_sum, g_cnt, mlpW1, mlpb1, mlpW2, mlpb2, out);
}